// Round 2
// baseline (301.527 us; speedup 1.0000x reference)
//
#include <hip/hip_runtime.h>

// VQ-VAE vector quantization forward — bit-exact emulation of the numpy ref.
// x: [32,64,64,64] f32 -> flat [N=131072, D=64]; embeddings: [D=64, K=512].
//
// np reference numerics we must match on argmin near-tie rows (~7 rows have
// best-vs-2nd gaps below the ulp(64)~7.6e-6 quantization of dists):
//   A   = np.sum(f*f, axis=1)   -> pairwise scalar 8-accumulator path (n=64)
//   B_k = np.sum(e*e, axis=0)   -> axis-0 reduce = sequential over d, no FMA
//   sim = flat @ emb            -> BLAS sgemm: sequential FMA chain over d
//   dist_k = fl( fl(A + B_k) - fl(2*sim_k) ), argmin = first min (strict <)
// out = fl(x + fl(q - x)); loss = 1.25 * mean((q-x)^2)  (fwd-equal branches)

constexpr int D = 64;
constexpr int K = 512;
constexpr int NROWS = 131072;           // 32*64*64*64 / 64
constexpr long long NELEM = 8388608LL;  // NROWS * D

// B_k = ||e_k||^2, sequential non-FMA over d (numpy axis-0 reduction order).
__global__ __launch_bounds__(512) void vq_prep(const float* __restrict__ emb,
                                               float* __restrict__ e2,
                                               float* __restrict__ loss_acc) {
    int k = threadIdx.x;  // 0..511
    float e0 = emb[k];
    float b = __fmul_rn(e0, e0);
    for (int d = 1; d < D; ++d) {
        float e = emb[d * K + k];
        b = __fadd_rn(b, __fmul_rn(e, e));
    }
    e2[k] = b;
    if (k == 0) loss_acc[0] = 0.f;
}

__global__ __launch_bounds__(256) void vq_main(const float* __restrict__ x,
                                               const float* __restrict__ emb,
                                               const float* __restrict__ e2,
                                               float* __restrict__ out,
                                               float* __restrict__ loss_acc) {
    const int row = blockIdx.x * 256 + threadIdx.x;  // grid covers NROWS exactly
    const float* xr = x + (size_t)row * D;

    // Row into registers (16 x float4, coalesced).
    float f[D];
    const float4* xr4 = reinterpret_cast<const float4*>(xr);
#pragma unroll
    for (int j = 0; j < D / 4; ++j) {
        float4 v = xr4[j];
        f[4 * j + 0] = v.x;
        f[4 * j + 1] = v.y;
        f[4 * j + 2] = v.z;
        f[4 * j + 3] = v.w;
    }

    // A = numpy pairwise sum of f*f, n=64, scalar 8-accumulator path:
    //   r[j] = m[j]; for i=8..56 step 8: r[j] += m[i+j];
    //   A = ((r0+r1)+(r2+r3)) + ((r4+r5)+(r6+r7))
    float r[8];
#pragma unroll
    for (int j = 0; j < 8; ++j) r[j] = __fmul_rn(f[j], f[j]);
#pragma unroll
    for (int i = 8; i < D; i += 8)
#pragma unroll
        for (int j = 0; j < 8; ++j)
            r[j] = __fadd_rn(r[j], __fmul_rn(f[i + j], f[i + j]));
    const float A =
        __fadd_rn(__fadd_rn(__fadd_rn(r[0], r[1]), __fadd_rn(r[2], r[3])),
                  __fadd_rn(__fadd_rn(r[4], r[5]), __fadd_rn(r[6], r[7])));

    float best = 3.0e38f;
    int bidx = 0;
    // k in chunks of 8; emb/e2 addresses wave-uniform -> scalar broadcast loads.
    for (int k0 = 0; k0 < K; k0 += 8) {
        float acc[8];
#pragma unroll
        for (int kk = 0; kk < 8; ++kk) acc[kk] = 0.f;
        // sim: single sequential FMA chain over d (BLAS sgemm microkernel order).
#pragma unroll
        for (int d = 0; d < D; ++d) {
            const float fd = f[d];
            const float* er = emb + d * K + k0;  // uniform
#pragma unroll
            for (int kk = 0; kk < 8; ++kk)
                acc[kk] = __fmaf_rn(fd, er[kk], acc[kk]);
        }
#pragma unroll
        for (int kk = 0; kk < 8; ++kk) {
            // dist = fl( fl(A + B) - fl(2*sim) )  -- exact np expression order
            float dist = __fsub_rn(__fadd_rn(A, e2[k0 + kk]),
                                   __fmul_rn(2.0f, acc[kk]));
            if (dist < best) {  // strict <: first-min tiebreak == np.argmin
                best = dist;
                bidx = k0 + kk;
            }
        }
    }

    // Gather winning column, write out = fl(x + fl(q-x)), accumulate loss.
    float lsum = 0.f;
    float* outr = out + (size_t)row * D;
    const float* eq = emb + bidx;
#pragma unroll
    for (int j = 0; j < D / 4; ++j) {
        float4 o;
        float q, t;
        q = eq[(4 * j + 0) * K]; t = __fsub_rn(q, f[4 * j + 0]);
        lsum = __fmaf_rn(t, t, lsum); o.x = __fadd_rn(f[4 * j + 0], t);
        q = eq[(4 * j + 1) * K]; t = __fsub_rn(q, f[4 * j + 1]);
        lsum = __fmaf_rn(t, t, lsum); o.y = __fadd_rn(f[4 * j + 1], t);
        q = eq[(4 * j + 2) * K]; t = __fsub_rn(q, f[4 * j + 2]);
        lsum = __fmaf_rn(t, t, lsum); o.z = __fadd_rn(f[4 * j + 2], t);
        q = eq[(4 * j + 3) * K]; t = __fsub_rn(q, f[4 * j + 3]);
        lsum = __fmaf_rn(t, t, lsum); o.w = __fadd_rn(f[4 * j + 3], t);
        reinterpret_cast<float4*>(outr)[j] = o;
    }

    // Loss reduce: wave shuffle -> LDS across 4 waves -> one atomic per block.
#pragma unroll
    for (int off = 32; off > 0; off >>= 1) lsum += __shfl_down(lsum, off, 64);
    __shared__ float wsum[4];
    const int lane = threadIdx.x & 63;
    const int wv = threadIdx.x >> 6;
    if (lane == 0) wsum[wv] = lsum;
    __syncthreads();
    if (threadIdx.x == 0)
        atomicAdd(loss_acc, wsum[0] + wsum[1] + wsum[2] + wsum[3]);
}

__global__ void vq_finalize(const float* __restrict__ loss_acc,
                            float* __restrict__ out_loss) {
    if (threadIdx.x == 0) {
        float m = loss_acc[0] / (float)NELEM;  // /2^23: exact
        out_loss[0] = 1.25f * m;               // == fl(0.25m + m), single rounding
    }
}

extern "C" void kernel_launch(void* const* d_in, const int* in_sizes, int n_in,
                              void* d_out, int out_size, void* d_ws, size_t ws_size,
                              hipStream_t stream) {
    const float* x = (const float*)d_in[0];
    const float* emb = (const float*)d_in[1];
    float* out = (float*)d_out;

    float* ws = (float*)d_ws;
    float* loss_acc = ws;      // 1 float
    float* e2 = ws + 64;       // 512 floats

    vq_prep<<<1, 512, 0, stream>>>(emb, e2, loss_acc);
    vq_main<<<NROWS / 256, 256, 0, stream>>>(x, emb, e2, out, loss_acc);
    vq_finalize<<<1, 64, 0, stream>>>(loss_acc, out + NELEM);
}